// Round 7
// baseline (174.203 us; speedup 1.0000x reference)
//
#include <hip/hip_runtime.h>
#include <hip/hip_bf16.h>

#define D_SRC 256
#define D_REL 128

typedef __bf16 bf16x8 __attribute__((ext_vector_type(8)));
typedef float f32x4 __attribute__((ext_vector_type(4)));

// ---------------- zero scratch ----------------
__global__ void zero_kernel(int* __restrict__ p, int n) {
    int i = blockIdx.x * 256 + threadIdx.x;
    if (i < n) p[i] = 0;
}

// ---------------- prep: arrange W (fp32 [256][128]) into 16x16x32 fragment order ----------------
// Wt[(ks*8+n)*64 + lane] = bf16x8 { W[ks*32 + (lane>>4)*8 + j][n*16 + (lane&15)] , j=0..7 }
// Used as the A-operand of mfma(Wt, x^T): A[m=lane&15][k] = W[k][m] = W^T.
__global__ __launch_bounds__(64) void prep_w_kernel(const float* __restrict__ W,
                                                    bf16x8* __restrict__ Wt) {
    int c = blockIdx.x;            // 0..63 = ks*8 + n
    int ks = c >> 3, n = c & 7;
    int lane = threadIdx.x;
    int col = n * 16 + (lane & 15);
    int k0 = ks * 32 + (lane >> 4) * 8;
    bf16x8 v;
#pragma unroll
    for (int j = 0; j < 8; ++j) v[j] = (__bf16)W[(size_t)(k0 + j) * D_REL + col];
    Wt[c * 64 + lane] = v;
}

// ---------------- projection: p = x @ W via D = (W^T)(x^T), W register-resident ----------------
// Block = 4 waves; wave w owns cols [w*32, w*32+32) for a 64-row block tile.
// Per wave: 16 resident W-frags (64 VGPR), 4 row-tiles x 2 half-K, software-pipelined
// x-loads pinned by sched_barrier(0). No LDS, no barriers, no B-loads in loop.
__global__ __launch_bounds__(256, 3) void proj_mfma_kernel(
    const float* __restrict__ x, const bf16x8* __restrict__ Wt,
    float* __restrict__ out, unsigned short* __restrict__ out_bf, int M) {
    int tid = threadIdx.x;
    int wid = tid >> 6, lane = tid & 63;
    int col0 = wid * 32;
    int r = lane & 15, kq = lane >> 4;
    int row0 = blockIdx.x * 64;

    // resident W^T fragments: wf[s][ks] covers cols col0+s*16.. , k = ks*32..
    bf16x8 wf[2][8];
#pragma unroll
    for (int s = 0; s < 2; ++s)
#pragma unroll
        for (int ks = 0; ks < 8; ++ks)
            wf[s][ks] = Wt[(ks * 8 + (col0 >> 4) + s) * 64 + lane];

    f32x4 lx[2][8];
    // prologue: load half-tile 0 (tile 0, k0=0)
    {
        int rowc = min(row0 + r, M - 1);
        const float* xp = x + (size_t)rowc * D_SRC + kq * 8;
#pragma unroll
        for (int i = 0; i < 4; ++i) {
            lx[0][2 * i + 0] = *(const f32x4*)(xp + i * 32);
            lx[0][2 * i + 1] = *(const f32x4*)(xp + i * 32 + 4);
        }
    }

    f32x4 acc0 = (f32x4)(0.f), acc1 = (f32x4)(0.f);

#pragma unroll
    for (int ht = 0; ht < 8; ++ht) {           // half-tile: tile = ht>>1, k0 = (ht&1)*128
        const int cur = ht & 1 ? 1 : 0;        // compile-time after unroll
        const int nxt = cur ^ 1;
        if (ht < 7) {
            int t1 = (ht + 1) >> 1, h1 = (ht + 1) & 1;
            int rowc = min(row0 + t1 * 16 + r, M - 1);
            const float* xp = x + (size_t)rowc * D_SRC + h1 * 128 + kq * 8;
#pragma unroll
            for (int i = 0; i < 4; ++i) {
                lx[nxt][2 * i + 0] = *(const f32x4*)(xp + i * 32);
                lx[nxt][2 * i + 1] = *(const f32x4*)(xp + i * 32 + 4);
            }
        }
        __builtin_amdgcn_sched_barrier(0);     // loads for ht+1 stay issued above
        // compute half-tile ht: 4 local k-steps
#pragma unroll
        for (int ks = 0; ks < 4; ++ks) {
            f32x4 a0 = lx[cur][2 * ks + 0], a1 = lx[cur][2 * ks + 1];
            bf16x8 xf;
            xf[0] = (__bf16)a0[0]; xf[1] = (__bf16)a0[1];
            xf[2] = (__bf16)a0[2]; xf[3] = (__bf16)a0[3];
            xf[4] = (__bf16)a1[0]; xf[5] = (__bf16)a1[1];
            xf[6] = (__bf16)a1[2]; xf[7] = (__bf16)a1[3];
            int gks = (ht & 1) * 4 + ks;
            acc0 = __builtin_amdgcn_mfma_f32_16x16x32_bf16(wf[0][gks], xf, acc0, 0, 0, 0);
            acc1 = __builtin_amdgcn_mfma_f32_16x16x32_bf16(wf[1][gks], xf, acc1, 0, 0, 0);
        }
        if (ht & 1) {
            // end of row-tile t = ht>>1: store D. lane holds p[row0+t*16+r][col0+s*16+kq*4+reg]
            int t = ht >> 1;
            int prow = row0 + t * 16 + r;
            if (prow < M) {
                size_t o0 = (size_t)prow * D_REL + col0 + kq * 4;
                size_t o1 = o0 + 16;
                *(f32x4*)(out + o0) = acc0;
                *(f32x4*)(out + o1) = acc1;
                ushort4 b0, b1;
                b0.x = __bfloat16_as_ushort(__float2bfloat16(acc0[0]));
                b0.y = __bfloat16_as_ushort(__float2bfloat16(acc0[1]));
                b0.z = __bfloat16_as_ushort(__float2bfloat16(acc0[2]));
                b0.w = __bfloat16_as_ushort(__float2bfloat16(acc0[3]));
                b1.x = __bfloat16_as_ushort(__float2bfloat16(acc1[0]));
                b1.y = __bfloat16_as_ushort(__float2bfloat16(acc1[1]));
                b1.z = __bfloat16_as_ushort(__float2bfloat16(acc1[2]));
                b1.w = __bfloat16_as_ushort(__float2bfloat16(acc1[3]));
                *(ushort4*)(out_bf + o0) = b0;
                *(ushort4*)(out_bf + o1) = b1;
            }
            acc0 = (f32x4)(0.f);
            acc1 = (f32x4)(0.f);
        }
    }
}

// ---------------- degree count + per-edge bucket position ----------------
__global__ void count_kernel(const int* __restrict__ edge_dst, int* __restrict__ deg_i,
                             int* __restrict__ pos_arr, int E) {
    int e = blockIdx.x * 256 + threadIdx.x;
    if (e < E) pos_arr[e] = atomicAdd(&deg_i[edge_dst[e]], 1);
}

// ---------------- 2-level exclusive scan ----------------
__global__ __launch_bounds__(1024) void scan_blocks(
    const int* __restrict__ deg_i, int* __restrict__ incl,
    int* __restrict__ bsums, int n) {
    int i = blockIdx.x * 1024 + threadIdx.x;
    int v = (i < n) ? deg_i[i] : 0;
    int lane = threadIdx.x & 63;
    int wid = threadIdx.x >> 6;
    int x = v;
#pragma unroll
    for (int off = 1; off < 64; off <<= 1) {
        int y = __shfl_up(x, off, 64);
        if (lane >= off) x += y;
    }
    __shared__ int wsum[16];
    if (lane == 63) wsum[wid] = x;
    __syncthreads();
    if (wid == 0 && lane < 16) {
        int s = wsum[lane];
#pragma unroll
        for (int off = 1; off < 16; off <<= 1) {
            int y = __shfl_up(s, off, 64);
            if (lane >= off) s += y;
        }
        wsum[lane] = s;
    }
    __syncthreads();
    int add = (wid > 0) ? wsum[wid - 1] : 0;
    x += add;
    if (i < n) incl[i] = x;
    if (threadIdx.x == 1023) bsums[blockIdx.x] = x;
}

__global__ __launch_bounds__(128) void scan_sums(int* __restrict__ bs, int nb) {
    __shared__ int tmp[128];
    int t = threadIdx.x;
    int v = (t < nb) ? bs[t] : 0;
    tmp[t] = v;
    __syncthreads();
    for (int off = 1; off < 128; off <<= 1) {
        int y = 0;
        if (t >= off) y = tmp[t - off];
        __syncthreads();
        tmp[t] += y;
        __syncthreads();
    }
    if (t < nb) bs[t] = tmp[t] - v;  // exclusive
}

__global__ __launch_bounds__(1024) void finalize_kernel(
    const int* __restrict__ deg_i, const int* __restrict__ incl,
    const int* __restrict__ bsums, int* __restrict__ row_start,
    float* __restrict__ deg_out, int n, int E) {
    int i = blockIdx.x * 1024 + threadIdx.x;
    if (i < n) {
        int off = bsums[blockIdx.x];
        row_start[i] = off + incl[i] - deg_i[i];
        deg_out[i] = (float)max(deg_i[i], 1);
    }
    if (i == 0) row_start[n] = E;
}

// ---------------- bucket fill (atomic-free) ----------------
__global__ void fill_kernel(const int* __restrict__ edge_src,
                            const int* __restrict__ edge_dst,
                            const int* __restrict__ row_start,
                            const int* __restrict__ pos_arr,
                            int* __restrict__ bucket, int E) {
    int e = blockIdx.x * 256 + threadIdx.x;
    if (e < E) {
        int d = edge_dst[e];
        bucket[row_start[d] + pos_arr[e]] = edge_src[e];
    }
}

// ---------------- gather: one wave per dst row, bf16 source, 4-deep pipeline ----------------
__global__ __launch_bounds__(256) void gather_kernel(
    const unsigned int* __restrict__ p_bf, const int* __restrict__ row_start,
    const int* __restrict__ bucket, const float* __restrict__ deg_out,
    float* __restrict__ dst, int n) {
    int row = blockIdx.x * 4 + (threadIdx.x >> 6);
    int lane = threadIdx.x & 63;
    if (row >= n) return;
    int beg = row_start[row], end = row_start[row + 1];
    float ax = 0.f, ay = 0.f;
    int idx = beg;
    for (; idx + 4 <= end; idx += 4) {
        int s0 = bucket[idx + 0];
        int s1 = bucket[idx + 1];
        int s2 = bucket[idx + 2];
        int s3 = bucket[idx + 3];
        unsigned int v0 = p_bf[(size_t)s0 * 64 + lane];
        unsigned int v1 = p_bf[(size_t)s1 * 64 + lane];
        unsigned int v2 = p_bf[(size_t)s2 * 64 + lane];
        unsigned int v3 = p_bf[(size_t)s3 * 64 + lane];
        ax += __uint_as_float(v0 << 16) + __uint_as_float(v1 << 16)
            + __uint_as_float(v2 << 16) + __uint_as_float(v3 << 16);
        ay += __uint_as_float(v0 & 0xffff0000u) + __uint_as_float(v1 & 0xffff0000u)
            + __uint_as_float(v2 & 0xffff0000u) + __uint_as_float(v3 & 0xffff0000u);
    }
    for (; idx < end; ++idx) {
        int s = bucket[idx];
        unsigned int v = p_bf[(size_t)s * 64 + lane];
        ax += __uint_as_float(v << 16);
        ay += __uint_as_float(v & 0xffff0000u);
    }
    float dinv = 1.0f / deg_out[row];
    float2 o;
    o.x = ax * dinv;
    o.y = ay * dinv;
    ((float2*)dst)[(size_t)row * 64 + lane] = o;
}

extern "C" void kernel_launch(void* const* d_in, const int* in_sizes, int n_in,
                              void* d_out, int out_size, void* d_ws, size_t ws_size,
                              hipStream_t stream) {
    const float* x_src = (const float*)d_in[0];
    const float* W_src = (const float*)d_in[2];
    const int* edge_src = (const int*)d_in[4];
    const int* edge_dst = (const int*)d_in[5];

    const int N_SRC = in_sizes[0] / D_SRC;
    const int N_DST = in_sizes[1] / D_SRC;
    const int E = in_sizes[4];

    float* out_dst = (float*)d_out;                          // [N_DST, 128]
    float* out_psrc = out_dst + (size_t)N_DST * D_REL;       // [N_SRC, 128]
    float* out_deg = out_psrc + (size_t)N_SRC * D_REL;       // [N_DST]

    int* deg_i = (int*)d_ws;               // N_DST
    int* incl = deg_i + N_DST;             // N_DST
    int* row_start = incl + N_DST;         // N_DST+1
    int* bsums = row_start + N_DST + 1;    // 128
    int* pos_arr = bsums + 128;            // E
    int* bucket = pos_arr + E;             // E
    size_t int_bytes = (size_t)(3 * N_DST + 1 + 128 + 2 * (size_t)E) * sizeof(int);
    size_t wt_off = (int_bytes + 255) & ~(size_t)255;
    bf16x8* Wt = (bf16x8*)((char*)d_ws + wt_off);            // 64 KB
    size_t pbf_off = wt_off + 65536;
    unsigned short* p_bf = (unsigned short*)((char*)d_ws + pbf_off);  // N_SRC*128 bf16

    // 1. zero deg_i
    zero_kernel<<<(N_DST + 255) / 256, 256, 0, stream>>>(deg_i, N_DST);
    // 2a. arrange W fragments (16x16x32 layout, used as A-operand = W^T)
    prep_w_kernel<<<64, 64, 0, stream>>>(W_src, Wt);
    // 2b. projection (register-resident W, pipelined x-loads) + bf16 copy
    proj_mfma_kernel<<<(N_SRC + 63) / 64, 256, 0, stream>>>(
        x_src, Wt, out_psrc, p_bf, N_SRC);
    // 3. degree count + per-edge position
    count_kernel<<<(E + 255) / 256, 256, 0, stream>>>(edge_dst, deg_i, pos_arr, E);
    // 4. scan
    int nb = (N_DST + 1023) / 1024;
    scan_blocks<<<nb, 1024, 0, stream>>>(deg_i, incl, bsums, N_DST);
    scan_sums<<<1, 128, 0, stream>>>(bsums, nb);
    finalize_kernel<<<nb, 1024, 0, stream>>>(deg_i, incl, bsums, row_start, out_deg, N_DST, E);
    // 5. bucket fill (atomic-free)
    fill_kernel<<<(E + 255) / 256, 256, 0, stream>>>(edge_src, edge_dst, row_start, pos_arr, bucket, E);
    // 6. gather + normalize (bf16 source)
    gather_kernel<<<(N_DST + 3) / 4, 256, 0, stream>>>(
        (const unsigned int*)p_bf, row_start, bucket, out_deg, out_dst, N_DST);
}

// Round 8
// 146.462 us; speedup vs baseline: 1.1894x; 1.1894x over previous
//
#include <hip/hip_runtime.h>
#include <hip/hip_bf16.h>

#define D_SRC 256
#define D_REL 128

typedef __bf16 bf16x8 __attribute__((ext_vector_type(8)));
typedef float f32x4 __attribute__((ext_vector_type(4)));

typedef const __attribute__((address_space(1))) void GASV;
typedef __attribute__((address_space(3))) void LASV;

// ---------------- zero scratch ----------------
__global__ void zero_kernel(int* __restrict__ p, int n) {
    int i = blockIdx.x * 256 + threadIdx.x;
    if (i < n) p[i] = 0;
}

// ---------------- prep: arrange W (fp32 [256][128]) into 16x16x32 fragment order ----------------
// Wt[(ks*8+n)*64 + lane] = bf16x8 { W[ks*32 + (lane>>4)*8 + j][n*16 + (lane&15)] , j=0..7 }
// Used as the A-operand of mfma(Wt, x^T): A[m][k] = W[k][m] = W^T.
__global__ __launch_bounds__(64) void prep_w_kernel(const float* __restrict__ W,
                                                    bf16x8* __restrict__ Wt) {
    int c = blockIdx.x;            // 0..63 = ks*8 + n
    int ks = c >> 3, n = c & 7;
    int lane = threadIdx.x;
    int col = n * 16 + (lane & 15);
    int k0 = ks * 32 + (lane >> 4) * 8;
    bf16x8 v;
#pragma unroll
    for (int j = 0; j < 8; ++j) v[j] = (__bf16)W[(size_t)(k0 + j) * D_REL + col];
    Wt[c * 64 + lane] = v;
}

// ---------------- projection: p = x @ W via D = (W^T)(x^T) ----------------
// Block = 4 waves, 32 rows x 128 cols. x staged to LDS via global_load_lds
// (coalesced, XOR-swizzled both sides). W^T frags pinned in registers via asm.
__global__ __launch_bounds__(256, 4) void proj_mfma_kernel(
    const float* __restrict__ x, const f32x4* __restrict__ Wt,
    float* __restrict__ out, unsigned short* __restrict__ out_bf, int M) {
    __shared__ float xlds[32 * 256];   // 32 KB: [row][64 slots of 16B], slot-swizzled
    int tid = threadIdx.x;
    int wid = tid >> 6, lane = tid & 63;
    int r = lane & 15, kq = lane >> 4;
    int row0 = blockIdx.x * 32;

    // ---- stage x rows [row0, row0+32): wave w stages rows w*8..w*8+7 ----
    // LDS dest = uniform base + lane*16 (phys slot = lane);
    // source slot = lane ^ (row&7)  => LDS[row][p] = x[row][p ^ (row&7)]
#pragma unroll
    for (int j = 0; j < 8; ++j) {
        int rl = wid * 8 + j;
        int grow = min(row0 + rl, M - 1);
        const float* src = x + (size_t)grow * D_SRC + ((lane ^ j) << 2);
        __builtin_amdgcn_global_load_lds((GASV*)src, (LASV*)&xlds[rl * 256], 16, 0, 0);
    }

    // ---- W^T fragments, register-resident (pinned: asm output can't be refetched) ----
    f32x4 wfv[2][8];
#pragma unroll
    for (int s = 0; s < 2; ++s)
#pragma unroll
        for (int ks = 0; ks < 8; ++ks)
            wfv[s][ks] = Wt[(ks * 8 + wid * 2 + s) * 64 + lane];
#pragma unroll
    for (int s = 0; s < 2; ++s)
#pragma unroll
        for (int ks = 0; ks < 8; ++ks)
            asm volatile("" : "+v"(wfv[s][ks]));

    __syncthreads();   // drains vmcnt: staging + wf loads complete

    f32x4 acc[2][2];
#pragma unroll
    for (int t = 0; t < 2; ++t)
#pragma unroll
        for (int s = 0; s < 2; ++s) acc[t][s] = (f32x4)(0.f);

    const f32x4* xl = (const f32x4*)xlds;
    int r8 = r & 7;
#pragma unroll
    for (int ks = 0; ks < 8; ++ks) {
        int q0 = ks * 8 + kq * 2;
#pragma unroll
        for (int t = 0; t < 2; ++t) {
            int rl = t * 16 + r;
            f32x4 a0 = xl[rl * 64 + (q0 ^ r8)];
            f32x4 a1 = xl[rl * 64 + ((q0 + 1) ^ r8)];
            bf16x8 xf;
            xf[0] = (__bf16)a0[0]; xf[1] = (__bf16)a0[1];
            xf[2] = (__bf16)a0[2]; xf[3] = (__bf16)a0[3];
            xf[4] = (__bf16)a1[0]; xf[5] = (__bf16)a1[1];
            xf[6] = (__bf16)a1[2]; xf[7] = (__bf16)a1[3];
            acc[t][0] = __builtin_amdgcn_mfma_f32_16x16x32_bf16(
                __builtin_bit_cast(bf16x8, wfv[0][ks]), xf, acc[t][0], 0, 0, 0);
            acc[t][1] = __builtin_amdgcn_mfma_f32_16x16x32_bf16(
                __builtin_bit_cast(bf16x8, wfv[1][ks]), xf, acc[t][1], 0, 0, 0);
        }
    }

    // ---- store: lane holds p[row0+t*16+r][col0 + s*16 + kq*4 + reg] ----
    int col0 = wid * 32;
#pragma unroll
    for (int t = 0; t < 2; ++t) {
        int prow = row0 + t * 16 + r;
        if (prow < M) {
            size_t o0 = (size_t)prow * D_REL + col0 + kq * 4;
            *(f32x4*)(out + o0) = acc[t][0];
            *(f32x4*)(out + o0 + 16) = acc[t][1];
            ushort4 b0, b1;
            b0.x = __bfloat16_as_ushort(__float2bfloat16(acc[t][0][0]));
            b0.y = __bfloat16_as_ushort(__float2bfloat16(acc[t][0][1]));
            b0.z = __bfloat16_as_ushort(__float2bfloat16(acc[t][0][2]));
            b0.w = __bfloat16_as_ushort(__float2bfloat16(acc[t][0][3]));
            b1.x = __bfloat16_as_ushort(__float2bfloat16(acc[t][1][0]));
            b1.y = __bfloat16_as_ushort(__float2bfloat16(acc[t][1][1]));
            b1.z = __bfloat16_as_ushort(__float2bfloat16(acc[t][1][2]));
            b1.w = __bfloat16_as_ushort(__float2bfloat16(acc[t][1][3]));
            *(ushort4*)(out_bf + o0) = b0;
            *(ushort4*)(out_bf + o0 + 16) = b1;
        }
    }
}

// ---------------- degree count + per-edge bucket position ----------------
__global__ void count_kernel(const int* __restrict__ edge_dst, int* __restrict__ deg_i,
                             int* __restrict__ pos_arr, int E) {
    int e = blockIdx.x * 256 + threadIdx.x;
    if (e < E) pos_arr[e] = atomicAdd(&deg_i[edge_dst[e]], 1);
}

// ---------------- 2-level exclusive scan ----------------
__global__ __launch_bounds__(1024) void scan_blocks(
    const int* __restrict__ deg_i, int* __restrict__ incl,
    int* __restrict__ bsums, int n) {
    int i = blockIdx.x * 1024 + threadIdx.x;
    int v = (i < n) ? deg_i[i] : 0;
    int lane = threadIdx.x & 63;
    int wid = threadIdx.x >> 6;
    int x = v;
#pragma unroll
    for (int off = 1; off < 64; off <<= 1) {
        int y = __shfl_up(x, off, 64);
        if (lane >= off) x += y;
    }
    __shared__ int wsum[16];
    if (lane == 63) wsum[wid] = x;
    __syncthreads();
    if (wid == 0 && lane < 16) {
        int s = wsum[lane];
#pragma unroll
        for (int off = 1; off < 16; off <<= 1) {
            int y = __shfl_up(s, off, 64);
            if (lane >= off) s += y;
        }
        wsum[lane] = s;
    }
    __syncthreads();
    int add = (wid > 0) ? wsum[wid - 1] : 0;
    x += add;
    if (i < n) incl[i] = x;
    if (threadIdx.x == 1023) bsums[blockIdx.x] = x;
}

__global__ __launch_bounds__(128) void scan_sums(int* __restrict__ bs, int nb) {
    __shared__ int tmp[128];
    int t = threadIdx.x;
    int v = (t < nb) ? bs[t] : 0;
    tmp[t] = v;
    __syncthreads();
    for (int off = 1; off < 128; off <<= 1) {
        int y = 0;
        if (t >= off) y = tmp[t - off];
        __syncthreads();
        tmp[t] += y;
        __syncthreads();
    }
    if (t < nb) bs[t] = tmp[t] - v;  // exclusive
}

__global__ __launch_bounds__(1024) void finalize_kernel(
    const int* __restrict__ deg_i, const int* __restrict__ incl,
    const int* __restrict__ bsums, int* __restrict__ row_start,
    float* __restrict__ deg_out, int n, int E) {
    int i = blockIdx.x * 1024 + threadIdx.x;
    if (i < n) {
        int off = bsums[blockIdx.x];
        row_start[i] = off + incl[i] - deg_i[i];
        deg_out[i] = (float)max(deg_i[i], 1);
    }
    if (i == 0) row_start[n] = E;
}

// ---------------- bucket fill (atomic-free) ----------------
__global__ void fill_kernel(const int* __restrict__ edge_src,
                            const int* __restrict__ edge_dst,
                            const int* __restrict__ row_start,
                            const int* __restrict__ pos_arr,
                            int* __restrict__ bucket, int E) {
    int e = blockIdx.x * 256 + threadIdx.x;
    if (e < E) {
        int d = edge_dst[e];
        bucket[row_start[d] + pos_arr[e]] = edge_src[e];
    }
}

// ---------------- gather: one wave per dst row, bf16 source, 4-deep pipeline ----------------
__global__ __launch_bounds__(256) void gather_kernel(
    const unsigned int* __restrict__ p_bf, const int* __restrict__ row_start,
    const int* __restrict__ bucket, const float* __restrict__ deg_out,
    float* __restrict__ dst, int n) {
    int row = blockIdx.x * 4 + (threadIdx.x >> 6);
    int lane = threadIdx.x & 63;
    if (row >= n) return;
    int beg = row_start[row], end = row_start[row + 1];
    float ax = 0.f, ay = 0.f;
    int idx = beg;
    for (; idx + 4 <= end; idx += 4) {
        int s0 = bucket[idx + 0];
        int s1 = bucket[idx + 1];
        int s2 = bucket[idx + 2];
        int s3 = bucket[idx + 3];
        unsigned int v0 = p_bf[(size_t)s0 * 64 + lane];
        unsigned int v1 = p_bf[(size_t)s1 * 64 + lane];
        unsigned int v2 = p_bf[(size_t)s2 * 64 + lane];
        unsigned int v3 = p_bf[(size_t)s3 * 64 + lane];
        ax += __uint_as_float(v0 << 16) + __uint_as_float(v1 << 16)
            + __uint_as_float(v2 << 16) + __uint_as_float(v3 << 16);
        ay += __uint_as_float(v0 & 0xffff0000u) + __uint_as_float(v1 & 0xffff0000u)
            + __uint_as_float(v2 & 0xffff0000u) + __uint_as_float(v3 & 0xffff0000u);
    }
    for (; idx < end; ++idx) {
        int s = bucket[idx];
        unsigned int v = p_bf[(size_t)s * 64 + lane];
        ax += __uint_as_float(v << 16);
        ay += __uint_as_float(v & 0xffff0000u);
    }
    float dinv = 1.0f / deg_out[row];
    float2 o;
    o.x = ax * dinv;
    o.y = ay * dinv;
    ((float2*)dst)[(size_t)row * 64 + lane] = o;
}

extern "C" void kernel_launch(void* const* d_in, const int* in_sizes, int n_in,
                              void* d_out, int out_size, void* d_ws, size_t ws_size,
                              hipStream_t stream) {
    const float* x_src = (const float*)d_in[0];
    const float* W_src = (const float*)d_in[2];
    const int* edge_src = (const int*)d_in[4];
    const int* edge_dst = (const int*)d_in[5];

    const int N_SRC = in_sizes[0] / D_SRC;
    const int N_DST = in_sizes[1] / D_SRC;
    const int E = in_sizes[4];

    float* out_dst = (float*)d_out;                          // [N_DST, 128]
    float* out_psrc = out_dst + (size_t)N_DST * D_REL;       // [N_SRC, 128]
    float* out_deg = out_psrc + (size_t)N_SRC * D_REL;       // [N_DST]

    int* deg_i = (int*)d_ws;               // N_DST
    int* incl = deg_i + N_DST;             // N_DST
    int* row_start = incl + N_DST;         // N_DST+1
    int* bsums = row_start + N_DST + 1;    // 128
    int* pos_arr = bsums + 128;            // E
    int* bucket = pos_arr + E;             // E
    size_t int_bytes = (size_t)(3 * N_DST + 1 + 128 + 2 * (size_t)E) * sizeof(int);
    size_t wt_off = (int_bytes + 255) & ~(size_t)255;
    bf16x8* Wt = (bf16x8*)((char*)d_ws + wt_off);            // 64 KB
    size_t pbf_off = wt_off + 65536;
    unsigned short* p_bf = (unsigned short*)((char*)d_ws + pbf_off);  // N_SRC*128 bf16

    // 1. zero deg_i
    zero_kernel<<<(N_DST + 255) / 256, 256, 0, stream>>>(deg_i, N_DST);
    // 2a. arrange W fragments (16x16x32 layout, used as A-operand = W^T)
    prep_w_kernel<<<64, 64, 0, stream>>>(W_src, Wt);
    // 2b. projection (LDS-staged x via global_load_lds, pinned resident W) + bf16 copy
    proj_mfma_kernel<<<(N_SRC + 31) / 32, 256, 0, stream>>>(
        x_src, (const f32x4*)Wt, out_psrc, p_bf, N_SRC);
    // 3. degree count + per-edge position
    count_kernel<<<(E + 255) / 256, 256, 0, stream>>>(edge_dst, deg_i, pos_arr, E);
    // 4. scan
    int nb = (N_DST + 1023) / 1024;
    scan_blocks<<<nb, 1024, 0, stream>>>(deg_i, incl, bsums, N_DST);
    scan_sums<<<1, 128, 0, stream>>>(bsums, nb);
    finalize_kernel<<<nb, 1024, 0, stream>>>(deg_i, incl, bsums, row_start, out_deg, N_DST, E);
    // 5. bucket fill (atomic-free)
    fill_kernel<<<(E + 255) / 256, 256, 0, stream>>>(edge_src, edge_dst, row_start, pos_arr, bucket, E);
    // 6. gather + normalize (bf16 source)
    gather_kernel<<<(N_DST + 3) / 4, 256, 0, stream>>>(
        (const unsigned int*)p_bf, row_start, bucket, out_deg, out_dst, N_DST);
}

// Round 9
// 141.334 us; speedup vs baseline: 1.2326x; 1.0363x over previous
//
#include <hip/hip_runtime.h>
#include <hip/hip_bf16.h>

#define D_SRC 256
#define D_REL 128

typedef __bf16 bf16x8 __attribute__((ext_vector_type(8)));
typedef float f32x4 __attribute__((ext_vector_type(4)));

typedef const __attribute__((address_space(1))) void GASV;
typedef __attribute__((address_space(3))) void LASV;

// ---------------- prep: arrange W (fp32 [256][128]) into 16x16x32 fragment order ----------------
// Wt[(ks*8+n)*64 + lane] = bf16x8 { W[ks*32 + (lane>>4)*8 + j][n*16 + (lane&15)] , j=0..7 }
// Used as the A-operand of mfma(Wt, x^T): A[m][k] = W[k][m] = W^T.
__global__ __launch_bounds__(64) void prep_w_kernel(const float* __restrict__ W,
                                                    bf16x8* __restrict__ Wt) {
    int c = blockIdx.x;            // 0..63 = ks*8 + n
    int ks = c >> 3, n = c & 7;
    int lane = threadIdx.x;
    int col = n * 16 + (lane & 15);
    int k0 = ks * 32 + (lane >> 4) * 8;
    bf16x8 v;
#pragma unroll
    for (int j = 0; j < 8; ++j) v[j] = (__bf16)W[(size_t)(k0 + j) * D_REL + col];
    Wt[c * 64 + lane] = v;
}

// ---------------- projection: persistent blocks, 2-phase double-buffered pipeline ----------------
// 512 blocks (2/CU, all resident), 4 waves each. Per iteration (32-row group):
// STAGE(next group -> other buf) ; compute(cur buf) ; stores ; vmcnt(8) ; s_barrier.
// W^T fragments register-pinned. x staged via global_load_lds, XOR-swizzled both sides.
__global__ __launch_bounds__(256, 2) void proj_mfma_kernel(
    const float* __restrict__ x, const f32x4* __restrict__ Wt,
    float* __restrict__ out, unsigned short* __restrict__ out_bf,
    int M, int ngroups, int nblocks) {
    __shared__ float xlds[2][32 * 256];   // 2 x 32KB
    int tid = threadIdx.x;
    int wid = tid >> 6, lane = tid & 63;
    int r = lane & 15, kq = lane >> 4;
    int r8 = r & 7;

    // stage group g into buffer buf: wave w stages rows w*8..w*8+7 of the group.
    // LDS phys slot = lane (dest uniform base + lane*16); source slot = lane ^ (row&7).
    auto stagef = [&](int buf, int g) {
        int base = g * 32;
#pragma unroll
        for (int j = 0; j < 8; ++j) {
            int rl = wid * 8 + j;
            int grow = min(base + rl, M - 1);
            const float* src = x + (size_t)grow * D_SRC + ((lane ^ j) << 2);
            __builtin_amdgcn_global_load_lds((GASV*)src, (LASV*)&xlds[buf][rl * 256], 16, 0, 0);
        }
    };

    // ---- W^T fragments, register-resident (asm pin prevents rematerialization) ----
    f32x4 wfv[2][8];
#pragma unroll
    for (int s = 0; s < 2; ++s)
#pragma unroll
        for (int ks = 0; ks < 8; ++ks)
            wfv[s][ks] = Wt[(ks * 8 + wid * 2 + s) * 64 + lane];
#pragma unroll
    for (int s = 0; s < 2; ++s)
#pragma unroll
        for (int ks = 0; ks < 8; ++ks)
            asm volatile("" : "+v"(wfv[s][ks]));    // forces completion + residency

    // prologue: stage first group
    int g0 = blockIdx.x;
    if (g0 < ngroups) stagef(0, g0);
    asm volatile("s_waitcnt vmcnt(0)" ::: "memory");
    __builtin_amdgcn_s_barrier();

    int cur = 0;
    for (int g = g0; g < ngroups; g += nblocks) {
        int gn = g + nblocks;
        if (gn < ngroups) stagef(cur ^ 1, gn);      // overlaps with compute below

        // ---- compute group g from xlds[cur] ----
        f32x4 acc[2][2];
#pragma unroll
        for (int t = 0; t < 2; ++t)
#pragma unroll
            for (int s = 0; s < 2; ++s) acc[t][s] = (f32x4)(0.f);

        const f32x4* xl = (const f32x4*)&xlds[cur][0];
#pragma unroll
        for (int ks = 0; ks < 8; ++ks) {
            int q0 = ks * 8 + kq * 2;
#pragma unroll
            for (int t = 0; t < 2; ++t) {
                int rl = t * 16 + r;
                f32x4 a0 = xl[rl * 64 + (q0 ^ r8)];
                f32x4 a1 = xl[rl * 64 + ((q0 + 1) ^ r8)];
                bf16x8 xf;
                xf[0] = (__bf16)a0[0]; xf[1] = (__bf16)a0[1];
                xf[2] = (__bf16)a0[2]; xf[3] = (__bf16)a0[3];
                xf[4] = (__bf16)a1[0]; xf[5] = (__bf16)a1[1];
                xf[6] = (__bf16)a1[2]; xf[7] = (__bf16)a1[3];
                acc[t][0] = __builtin_amdgcn_mfma_f32_16x16x32_bf16(
                    __builtin_bit_cast(bf16x8, wfv[0][ks]), xf, acc[t][0], 0, 0, 0);
                acc[t][1] = __builtin_amdgcn_mfma_f32_16x16x32_bf16(
                    __builtin_bit_cast(bf16x8, wfv[1][ks]), xf, acc[t][1], 0, 0, 0);
            }
        }

        // ---- store: lane holds p[g*32 + t*16 + r][wid*32 + s*16 + kq*4 + reg] ----
        int col0 = wid * 32;
#pragma unroll
        for (int t = 0; t < 2; ++t) {
            int prow = g * 32 + t * 16 + r;
            if (prow < M) {
                size_t o0 = (size_t)prow * D_REL + col0 + kq * 4;
                *(f32x4*)(out + o0) = acc[t][0];
                *(f32x4*)(out + o0 + 16) = acc[t][1];
                ushort4 b0, b1;
                b0.x = __bfloat16_as_ushort(__float2bfloat16(acc[t][0][0]));
                b0.y = __bfloat16_as_ushort(__float2bfloat16(acc[t][0][1]));
                b0.z = __bfloat16_as_ushort(__float2bfloat16(acc[t][0][2]));
                b0.w = __bfloat16_as_ushort(__float2bfloat16(acc[t][0][3]));
                b1.x = __bfloat16_as_ushort(__float2bfloat16(acc[t][1][0]));
                b1.y = __bfloat16_as_ushort(__float2bfloat16(acc[t][1][1]));
                b1.z = __bfloat16_as_ushort(__float2bfloat16(acc[t][1][2]));
                b1.w = __bfloat16_as_ushort(__float2bfloat16(acc[t][1][3]));
                *(ushort4*)(out_bf + o0) = b0;
                *(ushort4*)(out_bf + o0 + 16) = b1;
            }
        }

        // counted drain: 8 stage-gloads (oldest) must land; 8 stores may stay in flight.
        asm volatile("s_waitcnt vmcnt(8)" ::: "memory");
        __builtin_amdgcn_s_barrier();
        cur ^= 1;
    }
}

// ---------------- degree count + per-edge bucket position ----------------
__global__ void count_kernel(const int* __restrict__ edge_dst, int* __restrict__ deg_i,
                             int* __restrict__ pos_arr, int E) {
    int e = blockIdx.x * 256 + threadIdx.x;
    if (e < E) pos_arr[e] = atomicAdd(&deg_i[edge_dst[e]], 1);
}

// ---------------- 2-level exclusive scan ----------------
__global__ __launch_bounds__(1024) void scan_blocks(
    const int* __restrict__ deg_i, int* __restrict__ incl,
    int* __restrict__ bsums, int n) {
    int i = blockIdx.x * 1024 + threadIdx.x;
    int v = (i < n) ? deg_i[i] : 0;
    int lane = threadIdx.x & 63;
    int wid = threadIdx.x >> 6;
    int x = v;
#pragma unroll
    for (int off = 1; off < 64; off <<= 1) {
        int y = __shfl_up(x, off, 64);
        if (lane >= off) x += y;
    }
    __shared__ int wsum[16];
    if (lane == 63) wsum[wid] = x;
    __syncthreads();
    if (wid == 0 && lane < 16) {
        int s = wsum[lane];
#pragma unroll
        for (int off = 1; off < 16; off <<= 1) {
            int y = __shfl_up(s, off, 64);
            if (lane >= off) s += y;
        }
        wsum[lane] = s;
    }
    __syncthreads();
    int add = (wid > 0) ? wsum[wid - 1] : 0;
    x += add;
    if (i < n) incl[i] = x;
    if (threadIdx.x == 1023) bsums[blockIdx.x] = x;
}

__global__ __launch_bounds__(128) void scan_sums(int* __restrict__ bs, int nb) {
    __shared__ int tmp[128];
    int t = threadIdx.x;
    int v = (t < nb) ? bs[t] : 0;
    tmp[t] = v;
    __syncthreads();
    for (int off = 1; off < 128; off <<= 1) {
        int y = 0;
        if (t >= off) y = tmp[t - off];
        __syncthreads();
        tmp[t] += y;
        __syncthreads();
    }
    if (t < nb) bs[t] = tmp[t] - v;  // exclusive
}

__global__ __launch_bounds__(1024) void finalize_kernel(
    const int* __restrict__ deg_i, const int* __restrict__ incl,
    const int* __restrict__ bsums, int* __restrict__ row_start,
    float* __restrict__ deg_out, int n, int E) {
    int i = blockIdx.x * 1024 + threadIdx.x;
    if (i < n) {
        int off = bsums[blockIdx.x];
        row_start[i] = off + incl[i] - deg_i[i];
        deg_out[i] = (float)max(deg_i[i], 1);
    }
    if (i == 0) row_start[n] = E;
}

// ---------------- bucket fill (atomic-free) ----------------
__global__ void fill_kernel(const int* __restrict__ edge_src,
                            const int* __restrict__ edge_dst,
                            const int* __restrict__ row_start,
                            const int* __restrict__ pos_arr,
                            int* __restrict__ bucket, int E) {
    int e = blockIdx.x * 256 + threadIdx.x;
    if (e < E) {
        int d = edge_dst[e];
        bucket[row_start[d] + pos_arr[e]] = edge_src[e];
    }
}

// ---------------- gather: one wave per dst row, bf16 source, 8-deep pipeline ----------------
__global__ __launch_bounds__(256) void gather_kernel(
    const unsigned int* __restrict__ p_bf, const int* __restrict__ row_start,
    const int* __restrict__ bucket, const float* __restrict__ deg_out,
    float* __restrict__ dst, int n) {
    int row = blockIdx.x * 4 + (threadIdx.x >> 6);
    int lane = threadIdx.x & 63;
    if (row >= n) return;
    int beg = row_start[row], end = row_start[row + 1];
    float ax = 0.f, ay = 0.f;
    int idx = beg;
    for (; idx + 8 <= end; idx += 8) {
        int s[8];
        unsigned int v[8];
#pragma unroll
        for (int u = 0; u < 8; ++u) s[u] = bucket[idx + u];
#pragma unroll
        for (int u = 0; u < 8; ++u) v[u] = p_bf[(size_t)s[u] * 64 + lane];
#pragma unroll
        for (int u = 0; u < 8; ++u) {
            ax += __uint_as_float(v[u] << 16);
            ay += __uint_as_float(v[u] & 0xffff0000u);
        }
    }
    for (; idx + 4 <= end; idx += 4) {
        int s0 = bucket[idx + 0], s1 = bucket[idx + 1];
        int s2 = bucket[idx + 2], s3 = bucket[idx + 3];
        unsigned int v0 = p_bf[(size_t)s0 * 64 + lane];
        unsigned int v1 = p_bf[(size_t)s1 * 64 + lane];
        unsigned int v2 = p_bf[(size_t)s2 * 64 + lane];
        unsigned int v3 = p_bf[(size_t)s3 * 64 + lane];
        ax += __uint_as_float(v0 << 16) + __uint_as_float(v1 << 16)
            + __uint_as_float(v2 << 16) + __uint_as_float(v3 << 16);
        ay += __uint_as_float(v0 & 0xffff0000u) + __uint_as_float(v1 & 0xffff0000u)
            + __uint_as_float(v2 & 0xffff0000u) + __uint_as_float(v3 & 0xffff0000u);
    }
    for (; idx < end; ++idx) {
        int s = bucket[idx];
        unsigned int v = p_bf[(size_t)s * 64 + lane];
        ax += __uint_as_float(v << 16);
        ay += __uint_as_float(v & 0xffff0000u);
    }
    float dinv = 1.0f / deg_out[row];
    float2 o;
    o.x = ax * dinv;
    o.y = ay * dinv;
    ((float2*)dst)[(size_t)row * 64 + lane] = o;
}

extern "C" void kernel_launch(void* const* d_in, const int* in_sizes, int n_in,
                              void* d_out, int out_size, void* d_ws, size_t ws_size,
                              hipStream_t stream) {
    const float* x_src = (const float*)d_in[0];
    const float* W_src = (const float*)d_in[2];
    const int* edge_src = (const int*)d_in[4];
    const int* edge_dst = (const int*)d_in[5];

    const int N_SRC = in_sizes[0] / D_SRC;
    const int N_DST = in_sizes[1] / D_SRC;
    const int E = in_sizes[4];

    float* out_dst = (float*)d_out;                          // [N_DST, 128]
    float* out_psrc = out_dst + (size_t)N_DST * D_REL;       // [N_SRC, 128]
    float* out_deg = out_psrc + (size_t)N_SRC * D_REL;       // [N_DST]

    int* deg_i = (int*)d_ws;               // N_DST
    int* incl = deg_i + N_DST;             // N_DST
    int* row_start = incl + N_DST;         // N_DST+1
    int* bsums = row_start + N_DST + 1;    // 128
    int* pos_arr = bsums + 128;            // E
    int* bucket = pos_arr + E;             // E
    size_t int_bytes = (size_t)(3 * N_DST + 1 + 128 + 2 * (size_t)E) * sizeof(int);
    size_t wt_off = (int_bytes + 255) & ~(size_t)255;
    bf16x8* Wt = (bf16x8*)((char*)d_ws + wt_off);            // 64 KB
    size_t pbf_off = wt_off + 65536;
    unsigned short* p_bf = (unsigned short*)((char*)d_ws + pbf_off);  // N_SRC*128 bf16

    // 1. zero deg_i (memset node — graph-capturable)
    hipMemsetAsync(deg_i, 0, (size_t)N_DST * sizeof(int), stream);
    // 2a. arrange W fragments (16x16x32 layout, used as A-operand = W^T)
    prep_w_kernel<<<64, 64, 0, stream>>>(W_src, Wt);
    // 2b. projection: persistent 2-phase pipelined blocks
    {
        int ngroups = (N_SRC + 31) / 32;
        int nblocks = 512;
        proj_mfma_kernel<<<nblocks, 256, 0, stream>>>(
            x_src, (const f32x4*)Wt, out_psrc, p_bf, N_SRC, ngroups, nblocks);
    }
    // 3. degree count + per-edge position
    count_kernel<<<(E + 255) / 256, 256, 0, stream>>>(edge_dst, deg_i, pos_arr, E);
    // 4. scan
    int nb = (N_DST + 1023) / 1024;
    scan_blocks<<<nb, 1024, 0, stream>>>(deg_i, incl, bsums, N_DST);
    scan_sums<<<1, 128, 0, stream>>>(bsums, nb);
    finalize_kernel<<<nb, 1024, 0, stream>>>(deg_i, incl, bsums, row_start, out_deg, N_DST, E);
    // 5. bucket fill (atomic-free)
    fill_kernel<<<(E + 255) / 256, 256, 0, stream>>>(edge_src, edge_dst, row_start, pos_arr, bucket, E);
    // 6. gather + normalize (bf16 source)
    gather_kernel<<<(N_DST + 3) / 4, 256, 0, stream>>>(
        (const unsigned int*)p_bf, row_start, bucket, out_deg, out_dst, N_DST);
}